// Round 9
// baseline (3234.743 us; speedup 1.0000x reference)
//
#include <hip/hip_runtime.h>
#include <hip/hip_bf16.h>
#include <stdint.h>

// GatedGNN: B=256, N=80, D=1024, T=3
#define B_   256
#define N_   80
#define D_   1024
#define M_   (B_*N_)     // 20480 rows (b*80+node)
// f16 2-term plan. Abuf row (f16), SA2_=4096: [a_in(0:1024)|a_out(1024:2048)|h(2048:3072)|rh(3072:4096)]
#define SA2_ 4096
// W row (f16), SW_=6144: [wa_hi(0:2048)|wa_lo(2048:4096)|wu_hi(4096:5120)|wu_lo(5120:6144)]
#define SW_  6144
// BK=32 chunks: [0,64) a-part (K=2048), [64,96) u-part (K=1024).
#define KT_  96

typedef _Float16 half_t;
typedef __attribute__((ext_vector_type(8))) _Float16 f16x8;  // 8 f16 = 4 VGPRs
typedef __attribute__((ext_vector_type(4))) float f32x4;

#define SB0() __builtin_amdgcn_sched_barrier(0)

__device__ __forceinline__ void async_cp16(const void* g, void* l) {
  __builtin_amdgcn_global_load_lds((const __attribute__((address_space(1))) unsigned int*)g,
                                   (__attribute__((address_space(3))) unsigned int*)l,
                                   16, 0, 0);
}
__device__ __forceinline__ float sigm_(float x) { return 1.0f / (1.0f + __expf(-x)); }
__device__ __forceinline__ float tanh_(float x) { return 2.0f / (1.0f + __expf(-2.0f * x)) - 1.0f; }
// f16 hi/lo split: hi+lo reconstructs v to ~22 mantissa bits.
__device__ __forceinline__ void split_f16(float v, half_t& hi, half_t& lo) {
  hi = (half_t)v;
  lo = (half_t)(v - (float)hi);
}

// A-plane column + W hi/lo columns for K-chunk kt.
__device__ __forceinline__ void plane_offsets(int kt, int UBASE, int& acol, int& whi, int& wlo) {
  if (kt < 64) { const int c = kt * 32;        acol = c;         whi = c;        wlo = 2048 + c; }
  else         { const int r = (kt - 64) * 32; acol = UBASE + r; whi = 4096 + r; wlo = 5120 + r; }
}

// ---------------- weight packing (f16 hi/lo split): Wzr[2048][SW_], Wh[1024][SW_] --------------
__global__ __launch_bounds__(256) void pack_weights(
    const float* __restrict__ W1w, const float* __restrict__ W1u,
    const float* __restrict__ W2w, const float* __restrict__ W2u,
    const float* __restrict__ W3w, const float* __restrict__ W3u,
    half_t* __restrict__ Wzr, half_t* __restrict__ Wh) {
  int idx = blockIdx.x * 256 + threadIdx.x;     // [0, 3072*3072)
  int n = idx / 3072, k = idx - n * 3072;       // n: 0..3071 output row, k: source col
  const float *Ww, *Wu; int nr; half_t* outrow;
  if (n < 1024)      { Ww = W1w; Wu = W1u; nr = n;        outrow = Wzr + (size_t)n * SW_; }
  else if (n < 2048) { Ww = W2w; Wu = W2u; nr = n - 1024; outrow = Wzr + (size_t)n * SW_; }
  else               { Ww = W3w; Wu = W3u; nr = n - 2048; outrow = Wh + (size_t)(n - 2048) * SW_; }
  float v; int chi, clo;
  if (k < 2048) { v = Ww[nr * 2048 + k];          chi = k;               clo = 2048 + k; }
  else          { v = Wu[nr * 1024 + (k - 2048)]; chi = 4096 + (k-2048); clo = 5120 + (k - 2048); }
  half_t hi, lo; split_f16(v, hi, lo);
  outrow[chi] = hi; outrow[clo] = lo;
}

// ---------------- propagation: a_in/a_out = inM/outM @ h[b] (fp32) -> single-f16 Abuf ----------
__global__ __launch_bounds__(256) void prop_kernel(
    const float* __restrict__ h, const float* __restrict__ inM,
    const float* __restrict__ outM, half_t* __restrict__ Abuf) {
  const int b = blockIdx.x;                        // chunk-local batch index
  const int d = blockIdx.y * 256 + threadIdx.x;
  const float* hb = h + (size_t)b * N_ * D_ + d;
  float hreg[N_];
  #pragma unroll
  for (int m = 0; m < N_; ++m) hreg[m] = hb[m * D_];
  half_t* Ab = Abuf + (size_t)b * N_ * SA2_;
  #pragma unroll
  for (int m = 0; m < N_; ++m) Ab[m * SA2_ + 2048 + d] = (half_t)hreg[m];
  for (int n = 0; n < N_; ++n) {
    float ai = 0.f, ao = 0.f;
    #pragma unroll
    for (int m = 0; m < N_; ++m) {
      ai += inM[n * N_ + m] * hreg[m];
      ao += outM[n * N_ + m] * hreg[m];
    }
    Ab[n * SA2_ + d]        = (half_t)ai;
    Ab[n * SA2_ + 1024 + d] = (half_t)ao;
  }
}

// ---------------- MFMA GEMM, 160x128 tile, BK=32, f16 2-term (a * w_hi + a * w_lo) ------------
// wave-grid 2x2, wave-tile 80m x 64n, acc 5x4 (80 AGPR). 
// R9: counted-vmcnt DOUBLE-BUFFER at 3 blocks/CU -- the combo R1/R5 couldn't have:
//   f16 halved LDS to 26 KB, so dbuf = 52 KB and 3x52 = 156 <= 160 KB. First time both proven
//   mechanisms coexist: 3-blk cross-block overlap (R0/R4: ~+40% vs 2 blk) AND T4 counted
//   vmcnt (R5: +42% at fixed occupancy; stage(kt+2) in flight across ~2 iterations).
// Ordering contract per iteration kt (R5-verified):
//   vmcnt(c)  -> own stage(kt) landed, stage(kt+1)'s c loads stay in flight
//               c is per-wave: waves 0-1 issue 3A+4B=7, waves 2-3 issue 2A+4B=6 (the A-extra
//               branch tid<128 is wave-uniform, so each wave's count is a constant)
//   s_barrier -> all waves' stage(kt) visible
//   13 ds_reads buf[kt&1] -> regs ; lgkmcnt(0) ; s_barrier -> buf[kt&1] dead chip-wide
//   stage(kt+2) into buf[kt&1]  (flies across seg0+seg1 and all of iter kt+1)
//   seg0: a*w_hi (20 MFMA); seg1: a*w_lo (20 MFMA)
// No other VMEM inside the loop -> vmcnt counts exact. NO intra-iter lgkm phasing / setprio
// (R6 lesson: fights the compiler). Registers: 80 VGPR + 80 acc = 160 <= 170 cap @ (256,3).
// Precision: identical MFMA order to R8 -> bit-identical (absmax 0.0322 passed).
// Bank-conflict swizzle (verified 0): slot q holds global chunk q^((row>>1)&3).
template<bool IS_ZR>
__global__ __launch_bounds__(256, 3) void gemm_kernel(
    const half_t* __restrict__ Abuf,           // [rows][SA2_] chunk-local
    const half_t* __restrict__ W,              // [Nout][SW_]
    const float* __restrict__ bw1, const float* __restrict__ bu1,
    const float* __restrict__ bw2, const float* __restrict__ bu2,
    const float* __restrict__ hcur,            // [rows][1024] fp32, chunk-local
    float* __restrict__ zbuf,                  // [rows][1024] fp32, chunk-local
    half_t* __restrict__ rhbase,               // = Abuf (rh at col 3072)
    float* __restrict__ hout,
    int mtiles) {
  __shared__ f16x8 ldsA[1280];   // 20 KB: dbuf(2) x 160 m-rows x 4 chunks
  __shared__ f16x8 ldsB[2048];   // 32 KB: dbuf(2) x plane(2) x 128 n-rows x 4 chunks

  const int ntiles = IS_ZR ? 16 : 8;           // 128-wide n tiles
  int mt, nt;
  if ((mtiles & 7) == 0) {
    const int flat = blockIdx.x;
    const int strip = mtiles >> 3;             // m-tiles per XCD
    const int xcd = flat & 7;
    const int loc = flat >> 3;                 // [0, strip*ntiles)
    mt = xcd * strip + loc / ntiles;
    nt = loc - (loc / ntiles) * ntiles;
  } else {
    mt = blockIdx.x / ntiles;
    nt = blockIdx.x - mt * ntiles;
  }
  const int m0 = mt * 160;
  const int n0 = nt * 128;

  const int tid  = threadIdx.x;
  const int lane = tid & 63;
  const int wave = tid >> 6;
  const int wm   = (wave & 1) * 80;
  const int wn   = (wave >> 1) * 64;
  const int l15  = lane & 15;
  const int l4   = lane >> 4;
  const int UBASE = IS_ZR ? 2048 : 3072;   // u-operand: h for ZR, r*h for H

  f32x4 acc[5][4];
  #pragma unroll
  for (int i = 0; i < 5; ++i)
    #pragma unroll
    for (int j = 0; j < 4; ++j) acc[i][j] = (f32x4){0.f, 0.f, 0.f, 0.f};

  // swizzled, loop-invariant operand read offsets (slot units of 16B)
  const int arow = wm + l15;
  const int brow = wn + l15;
  const int aoff = arow * 4 + (l4 ^ ((arow >> 1) & 3));
  const int boff = brow * 4 + (l4 ^ ((brow >> 1) & 3));

  // staging into buffer BUF: A 640 slots = 2/thread + 1 extra for waves 0-1 (wave-uniform);
  // B 1024 slots = 4/thread. Global chunk pre-swizzled by q^((row>>1)&3); LDS dest linear.
  // Per-tile load count: waves 0-1 -> 7, waves 2-3 -> 6 (used by the counted vmcnt below).
  #define STAGE_TILE(BUF, ACOL, WHI, WLO) do {                                                 \
      _Pragma("unroll")                                                                        \
      for (int i_ = 0; i_ < 2; ++i_) {                                                         \
        const int cidx = i_ * 256 + tid;                                                       \
        const int q  = cidx & 3;                                                               \
        const int mm = cidx >> 2;                                                              \
        const int qg = q ^ ((mm >> 1) & 3);                                                    \
        async_cp16(Abuf + (size_t)(m0 + mm) * SA2_ + (ACOL) + qg * 8,                          \
                   &ldsA[(BUF) * 640 + cidx]);                                                 \
      }                                                                                        \
      if (tid < 128) {                           /* waves 0,1 fully active: slots 512-639 */   \
        const int cidx = 512 + tid;                                                            \
        const int q  = cidx & 3;                                                               \
        const int mm = cidx >> 2;                                                              \
        const int qg = q ^ ((mm >> 1) & 3);                                                    \
        async_cp16(Abuf + (size_t)(m0 + mm) * SA2_ + (ACOL) + qg * 8,                          \
                   &ldsA[(BUF) * 640 + cidx]);                                                 \
      }                                                                                        \
      _Pragma("unroll")                                                                        \
      for (int j_ = 0; j_ < 4; ++j_) {                                                         \
        const int cidx = j_ * 256 + tid;                                                       \
        const int pl = cidx >> 9;                                                              \
        const int q  = cidx & 3;                                                               \
        const int nn = (cidx >> 2) & 127;                                                      \
        const int qg = q ^ ((nn >> 1) & 3);                                                    \
        async_cp16(W + (size_t)(n0 + nn) * SW_ + (pl ? (WLO) : (WHI)) + qg * 8,                \
                   &ldsB[(BUF) * 1024 + cidx]);                                                \
      }                                                                                        \
    } while (0)

  // prologue: stage tiles 0 and 1 (up to 14 loads in flight)
  int acol, whi, wlo;
  plane_offsets(0, UBASE, acol, whi, wlo);
  STAGE_TILE(0, acol, whi, wlo);
  plane_offsets(1, UBASE, acol, whi, wlo);
  STAGE_TILE(1, acol, whi, wlo);

  const bool wlohalf = (wave < 2);             // wave-uniform: this wave issues 7 loads/tile

  for (int kt = 0; kt < KT_; ++kt) {
    // tile-ready wait: own stage(kt) landed; keep stage(kt+1)'s loads in flight.
    if (kt < KT_ - 1) {
      if (wlohalf) { asm volatile("s_waitcnt vmcnt(7)" ::: "memory"); }
      else         { asm volatile("s_waitcnt vmcnt(6)" ::: "memory"); }
    } else {
      asm volatile("s_waitcnt vmcnt(0)" ::: "memory");
    }
    SB0();
    __builtin_amdgcn_s_barrier();              // all waves' stage(kt) visible
    SB0();

    const int abase = (kt & 1) * 640;
    const int bbase = (kt & 1) * 1024;
    f16x8 af[5], bb_h[4], bb_l[4];
    #pragma unroll
    for (int mi = 0; mi < 5; ++mi) af[mi] = ldsA[abase + aoff + mi * 64];
    #pragma unroll
    for (int ni = 0; ni < 4; ++ni) { bb_h[ni] = ldsB[bbase + boff + ni * 64];
                                     bb_l[ni] = ldsB[bbase + 512 + boff + ni * 64]; }
    asm volatile("s_waitcnt lgkmcnt(0)" ::: "memory");
    SB0();
    __builtin_amdgcn_s_barrier();              // buf[kt&1] dead chip-wide
    SB0();

    if (kt + 2 < KT_) {                        // stage kt+2 into the buffer just vacated
      plane_offsets(kt + 2, UBASE, acol, whi, wlo);
      STAGE_TILE(kt & 1, acol, whi, wlo);
    }

    #pragma unroll
    for (int mi = 0; mi < 5; ++mi)             // seg0: a * w_hi
      #pragma unroll
      for (int ni = 0; ni < 4; ++ni)
        acc[mi][ni] = __builtin_amdgcn_mfma_f32_16x16x32_f16(af[mi], bb_h[ni], acc[mi][ni], 0, 0, 0);
    #pragma unroll
    for (int mi = 0; mi < 5; ++mi)             // seg1: a * w_lo
      #pragma unroll
      for (int ni = 0; ni < 4; ++ni)
        acc[mi][ni] = __builtin_amdgcn_mfma_f32_16x16x32_f16(af[mi], bb_l[ni], acc[mi][ni], 0, 0, 0);
  }
  #undef STAGE_TILE

  // epilogue: C/D layout col = lane&15, row = (lane>>4)*4 + reg
  #pragma unroll
  for (int mi = 0; mi < 5; ++mi) {
    #pragma unroll
    for (int p = 0; p < 4; ++p) {
      const int m = m0 + wm + mi * 16 + l4 * 4 + p;
      #pragma unroll
      for (int ni = 0; ni < 4; ++ni) {
        const int n = n0 + wn + ni * 16 + l15;
        float v = acc[mi][ni][p];
        if (IS_ZR) {
          if (n < 1024) {
            zbuf[(size_t)m * 1024 + n] = sigm_(v + bw1[n] + bu1[n]);
          } else {
            const int nn2 = n - 1024;
            float r = sigm_(v + bw2[nn2] + bu2[nn2]);
            float rh = r * hcur[(size_t)m * 1024 + nn2];
            rhbase[(size_t)m * SA2_ + 3072 + nn2] = (half_t)rh;
          }
        } else {
          float hc = tanh_(v + bw1[n] + bu1[n]);
          float z  = zbuf[(size_t)m * 1024 + n];
          float ho = hcur[(size_t)m * 1024 + n];
          hout[(size_t)m * 1024 + n] = (1.0f - z) * ho + z * hc;
        }
      }
    }
  }
}

extern "C" void kernel_launch(void* const* d_in, const int* in_sizes, int n_in,
                              void* d_out, int out_size, void* d_ws, size_t ws_size,
                              hipStream_t stream) {
  const float* x    = (const float*)d_in[0];
  const float* inM  = (const float*)d_in[1];
  const float* outM = (const float*)d_in[2];
  const float* W1w  = (const float*)d_in[3];
  const float* b1w  = (const float*)d_in[4];
  const float* W1u  = (const float*)d_in[5];
  const float* b1u  = (const float*)d_in[6];
  const float* W2w  = (const float*)d_in[7];
  const float* b2w  = (const float*)d_in[8];
  const float* W2u  = (const float*)d_in[9];
  const float* b2u  = (const float*)d_in[10];
  const float* W3w  = (const float*)d_in[11];
  const float* b3w  = (const float*)d_in[12];
  const float* W3u  = (const float*)d_in[13];
  const float* b3u  = (const float*)d_in[14];
  float* hout = (float*)d_out;   // h lives in d_out across timesteps

  char* ws = (char*)d_ws;
  half_t* Wzr = (half_t*)ws;                                 // 2048*6144*2 = 25,165,824 B
  half_t* Wh  = (half_t*)(ws + 25165824);                    // 1024*6144*2 = 12,582,912 B
  const size_t fixed = 37748736;
  // per-batch-element chunk cost: Abuf 80*SA2_*2 + zbuf 80*1024*4 = 983,040 B
  int Rb = 256;                                              // batch elems per chunk (mult of 8)
  while (Rb > 8 && fixed + (size_t)Rb * 983040ull > ws_size) Rb -= 8;
  float* zbuf = (float*)(ws + fixed);                        // Rb*80*1024*4
  half_t* Abuf = (half_t*)(ws + fixed + (size_t)Rb * 327680ull);

  pack_weights<<<(3072 * 3072) / 256, 256, 0, stream>>>(
      W1w, W1u, W2w, W2u, W3w, W3u, Wzr, Wh);

  for (int t = 0; t < 3; ++t) {
    const float* hsrc = (t == 0) ? x : (const float*)hout;
    for (int b0 = 0; b0 < B_; b0 += Rb) {
      const int nb = (B_ - b0 < Rb) ? (B_ - b0) : Rb;
      const int rows = N_ * nb;                  // 80*nb, nb mult of 8 -> /160 integral
      const int mtiles = rows / 160;
      const float* hc = hsrc + (size_t)b0 * N_ * D_;
      prop_kernel<<<dim3(nb, D_ / 256), 256, 0, stream>>>(hc, inM, outM, Abuf);
      gemm_kernel<true><<<mtiles * 16, 256, 0, stream>>>(
          Abuf, Wzr, b1w, b1u, b2w, b2u, hc, zbuf, Abuf, nullptr, mtiles);
      gemm_kernel<false><<<mtiles * 8, 256, 0, stream>>>(
          Abuf, Wh, b3w, b3u, nullptr, nullptr, hc, zbuf, nullptr,
          hout + (size_t)b0 * N_ * D_, mtiles);
    }
  }
}